// Round 9
// baseline (59.689 us; speedup 1.0000x reference)
//
#include <hip/hip_runtime.h>
#include <hip/hip_bf16.h>

// B=64, T=2048, D=U=128 (fixed shape)
#define DD 128
#define UU 128
#define SEQ_T 2048
#define ROWS 64           // rows per tile
#define NTILE 2           // tiles per block (cross-tile reg prefetch)
#define PART_STRIDE 132   // per-tile partial: [m, l, pad, pad, ctx[128]]

typedef __attribute__((ext_vector_type(8))) short short8;   // 8 bf16
typedef __attribute__((ext_vector_type(4))) float f32x4;    // MFMA C/D

__device__ __forceinline__ unsigned short f2bf(float f) {   // HW RNE cvt
  return __builtin_bit_cast(unsigned short, __float2bfloat16(f));
}
__device__ __forceinline__ float bf2f(unsigned short s) {
  return __uint_as_float(((unsigned)s) << 16);
}
__device__ __forceinline__ float fast_tanh(float v) {
  float z = __expf(2.0f * v);
  return 1.0f - __fdividef(2.0f, z + 1.0f);
}

// One-shot: Wt[u][d] = bf16(W1[d][u] + W2[d][u]); bias[u] = b1[u]+b2[u]
__global__ void prep_kernel(const float* __restrict__ W1w, const float* __restrict__ W1b,
                            const float* __restrict__ W2w, const float* __restrict__ W2b,
                            unsigned short* __restrict__ wt_g, float* __restrict__ bias_g)
{
  int i = blockIdx.x * 256 + threadIdx.x;   // 16384 = 128*128
  int u = i >> 7, d = i & 127;
  float s = W1w[(size_t)d * UU + u] + W2w[(size_t)d * UU + u];
  wt_g[(size_t)u * DD + d] = f2bf(s);
  if (i < UU) bias_g[i] = W1b[i] + W2b[i];
}

// Persistent fused kernel: 2 tiles of 64 rows per block; tile t+1's global
// loads are issued right after barrier A and consumed (cvt->regs) BEFORE
// barrier B, so no __syncthreads ever drains an in-flight prefetch.
__global__ __launch_bounds__(256, 3)
void fused_score_ctx(const float* __restrict__ x,
                     const unsigned short* __restrict__ wt_g,
                     const float* __restrict__ bias_g,
                     const float* __restrict__ Vw,
                     float* __restrict__ part)
{
  __shared__ __align__(16) unsigned short xs[2][ROWS * DD];  // 2x16 KB swizzled
  __shared__ __align__(16) float spart[4][ROWS];             // per-wave score partials
  __shared__ __align__(16) float pctx_red[4][DD];            // per-wave ctx partials

  const int tid = threadIdx.x;
  const int blk = blockIdx.x;
  const int w = tid >> 6, l = tid & 63, lx = l & 15, lq = l >> 4;
  const int tau0 = blk * NTILE;

  // ---- prologue: issue tile-0 x loads first (longest latency) ----
  float4 xr[8];
  {
    const float* xb = x + (size_t)tau0 * ROWS * DD;
    #pragma unroll
    for (int it = 0; it < 4; ++it) {
      int F = tid + 256 * it;            // 1024 granules of 8 elems
      int row = F >> 4, g = F & 15;
      const float* src = xb + (size_t)row * DD + g * 8;
      xr[2 * it]     = *reinterpret_cast<const float4*>(src);
      xr[2 * it + 1] = *reinterpret_cast<const float4*>(src + 4);
    }
  }

  // ---- B fragments + V/bias for this wave's 32 u-columns (L2-hit) ----
  short8 Bf[2][4];
  float vs[2], bs[2];
  #pragma unroll
  for (int nf = 0; nf < 2; ++nf) {
    const int u = 32 * w + 16 * nf + lx;
    vs[nf] = Vw[u];
    bs[nf] = bias_g[u];
    #pragma unroll
    for (int kf = 0; kf < 4; ++kf)
      Bf[nf][kf] = *reinterpret_cast<const short8*>(
          wt_g + (size_t)u * DD + 32 * kf + 8 * lq);
  }

  // ---- cvt tile 0 -> bf16 regs ----
  short8 pk[4];
  #pragma unroll
  for (int it = 0; it < 4; ++it) {
    float4 v0 = xr[2 * it], v1 = xr[2 * it + 1];
    short8 p;
    p[0] = (short)f2bf(v0.x); p[1] = (short)f2bf(v0.y);
    p[2] = (short)f2bf(v0.z); p[3] = (short)f2bf(v0.w);
    p[4] = (short)f2bf(v1.x); p[5] = (short)f2bf(v1.y);
    p[6] = (short)f2bf(v1.z); p[7] = (short)f2bf(v1.w);
    pk[it] = p;
  }

  for (int t = 0; t < NTILE; ++t) {
    unsigned short* xb = xs[t & 1];

    // ---- write converted regs -> swizzled LDS ----
    #pragma unroll
    for (int it = 0; it < 4; ++it) {
      int F = tid + 256 * it;
      int row = F >> 4, g = F & 15;
      *reinterpret_cast<short8*>(xb + row * DD + ((g ^ (row & 15)) << 3)) = pk[it];
    }
    __syncthreads();   // A: xs[t&1] ready; no global loads outstanding

    // ---- issue next-tile loads; stay in flight until cvt below ----
    if (t + 1 < NTILE) {
      const float* nb = x + (size_t)(tau0 + t + 1) * ROWS * DD;
      #pragma unroll
      for (int it = 0; it < 4; ++it) {
        int F = tid + 256 * it;
        int row = F >> 4, g = F & 15;
        const float* src = nb + (size_t)row * DD + g * 8;
        xr[2 * it]     = *reinterpret_cast<const float4*>(src);
        xr[2 * it + 1] = *reinterpret_cast<const float4*>(src + 4);
      }
    }

    // ---- GEMM: 64 rows x wave's 32 u; A from LDS, B from regs ----
    f32x4 acc[4][2];
    #pragma unroll
    for (int mf = 0; mf < 4; ++mf) {
      acc[mf][0] = (f32x4){0.f, 0.f, 0.f, 0.f};
      acc[mf][1] = (f32x4){0.f, 0.f, 0.f, 0.f};
    }
    #pragma unroll
    for (int kf = 0; kf < 4; ++kf) {
      const int gs8 = ((4 * kf + lq) ^ lx) << 3;   // swizzle key: row&15 == lx
      #pragma unroll
      for (int mf = 0; mf < 4; ++mf) {
        short8 a = *reinterpret_cast<const short8*>(xb + (16 * mf + lx) * DD + gs8);
        acc[mf][0] = __builtin_amdgcn_mfma_f32_16x16x32_bf16(a, Bf[0][kf], acc[mf][0], 0, 0, 0);
        acc[mf][1] = __builtin_amdgcn_mfma_f32_16x16x32_bf16(a, Bf[1][kf], acc[mf][1], 0, 0, 0);
      }
    }

    // ---- per-wave score partials over this wave's u ----
    #pragma unroll
    for (int mf = 0; mf < 4; ++mf) {
      #pragma unroll
      for (int r = 0; r < 4; ++r) {
        float p = vs[0] * fast_tanh(acc[mf][0][r] + bs[0])
                + vs[1] * fast_tanh(acc[mf][1][r] + bs[1]);
        p += __shfl_xor(p, 1);
        p += __shfl_xor(p, 2);
        p += __shfl_xor(p, 4);
        p += __shfl_xor(p, 8);
        if (lx == 0) spart[w][16 * mf + 4 * lq + r] = p;   // C/D row = 4lq+r
      }
    }

    // ---- consume prefetched loads BEFORE barrier B (no drain at B) ----
    if (t + 1 < NTILE) {
      #pragma unroll
      for (int it = 0; it < 4; ++it) {
        float4 v0 = xr[2 * it], v1 = xr[2 * it + 1];
        short8 p;
        p[0] = (short)f2bf(v0.x); p[1] = (short)f2bf(v0.y);
        p[2] = (short)f2bf(v0.z); p[3] = (short)f2bf(v0.w);
        p[4] = (short)f2bf(v1.x); p[5] = (short)f2bf(v1.y);
        p[6] = (short)f2bf(v1.z); p[7] = (short)f2bf(v1.w);
        pk[it] = p;
      }
    }
    __syncthreads();   // B: spart ready

    // ---- softmax stats: row = lane (each wave holds all 64 rows) ----
    float sv = (spart[0][l] + spart[1][l]) + (spart[2][l] + spart[3][l]);
    float m = sv;
    #pragma unroll
    for (int off = 1; off < 64; off <<= 1) m = fmaxf(m, __shfl_xor(m, off));
    float e = __expf(sv - m);
    float lsum = e;
    #pragma unroll
    for (int off = 1; off < 64; off <<= 1) lsum += __shfl_xor(lsum, off);

    // ---- partial context: wave w covers rows [16w,16w+16) via shfl(e) ----
    {
      const int gd = l & 15;            // d-granule (8 d's)
      float ca[8];
      #pragma unroll
      for (int e2 = 0; e2 < 8; ++e2) ca[e2] = 0.0f;
      #pragma unroll
      for (int k = 0; k < 4; ++k) {
        int row = 16 * w + 4 * (l >> 4) + k;    // in [16w, 16w+16)
        float wgt = __shfl(e, row);              // lane 'row' holds e for row
        short8 xv = *reinterpret_cast<const short8*>(
            xb + row * DD + ((gd ^ (row & 15)) << 3));
        #pragma unroll
        for (int e2 = 0; e2 < 8; ++e2)
          ca[e2] = fmaf(wgt, bf2f((unsigned short)xv[e2]), ca[e2]);
      }
      #pragma unroll
      for (int e2 = 0; e2 < 8; ++e2) {
        ca[e2] += __shfl_xor(ca[e2], 16);
        ca[e2] += __shfl_xor(ca[e2], 32);
      }
      if ((l >> 4) == 0) {              // lanes 0..15: gd == l
        #pragma unroll
        for (int e2 = 0; e2 < 8; ++e2) pctx_red[w][gd * 8 + e2] = ca[e2];
      }
    }
    __syncthreads();   // C: pctx ready; also spaces xs buffer reuse

    float* prec = part + (size_t)(tau0 + t) * PART_STRIDE;
    if (tid < 128) {
      float c0 = (pctx_red[0][tid] + pctx_red[1][tid]) +
                 (pctx_red[2][tid] + pctx_red[3][tid]);
      prec[4 + tid] = c0;
    }
    if (tid == 0) { prec[0] = m; prec[1] = lsum; }
  }
}

// Flash-style combine of 32 per-tile partials per batch row.
__global__ void combine_kernel(const float* __restrict__ part,
                               float* __restrict__ out, int chunks)
{
  int b = blockIdx.x;
  int d = threadIdx.x;  // 128
  float mg = -3.0e38f;
  for (int i = 0; i < chunks; ++i)
    mg = fmaxf(mg, part[(size_t)(b * chunks + i) * PART_STRIDE]);
  float den = 0.0f, num = 0.0f;
  for (int i = 0; i < chunks; ++i) {
    const float* p = part + (size_t)(b * chunks + i) * PART_STRIDE;
    float sc = __expf(p[0] - mg);
    den = fmaf(sc, p[1], den);
    num = fmaf(sc, p[4 + d], num);
  }
  out[(size_t)b * DD + d] = __fdividef(num, den);
}

extern "C" void kernel_launch(void* const* d_in, const int* in_sizes, int n_in,
                              void* d_out, int out_size, void* d_ws, size_t ws_size,
                              hipStream_t stream)
{
  const float* x   = (const float*)d_in[0];
  const float* W1w = (const float*)d_in[1];
  const float* W1b = (const float*)d_in[2];
  const float* W2w = (const float*)d_in[3];
  const float* W2b = (const float*)d_in[4];
  const float* Vw  = (const float*)d_in[5];
  // d_in[6] = V_b: constant on scores, cancels in softmax.

  const int bt = in_sizes[0] / DD;       // 131072
  const int ntiles = bt / ROWS;          // 2048
  const int nblk = ntiles / NTILE;       // 1024
  const int B = bt / SEQ_T;              // 64
  const int chunks = SEQ_T / ROWS;       // 32

  const size_t part_bytes = (size_t)ntiles * PART_STRIDE * sizeof(float);  // ~1.08 MB
  float* part = (float*)d_ws;
  unsigned short* wt_g = (unsigned short*)((char*)d_ws + part_bytes);
  float* bias_g = (float*)((char*)d_ws + part_bytes + 32768);

  prep_kernel<<<64, 256, 0, stream>>>(W1w, W1b, W2w, W2b, wt_g, bias_g);
  fused_score_ctx<<<nblk, 256, 0, stream>>>(x, wt_g, bias_g, Vw, part);
  combine_kernel<<<B, 128, 0, stream>>>(part, (float*)d_out, chunks);
}

// Round 10
// 40.748 us; speedup vs baseline: 1.4649x; 1.4649x over previous
//
#include <hip/hip_runtime.h>
#include <hip/hip_bf16.h>

// B=64, T=2048, D=U=128 (fixed shape)
#define DD 128
#define UU 128
#define SEQ_T 2048
#define ROWS 64           // rows per score-chunk
#define NCHUNK 32         // chunks per batch (SEQ_T/ROWS)

typedef __attribute__((ext_vector_type(8))) short short8;   // 8 bf16
typedef __attribute__((ext_vector_type(4))) float f32x4;    // MFMA C/D

__device__ __forceinline__ unsigned short f2bf(float f) {   // RNE fp32->bf16
  unsigned u = __float_as_uint(f);
  u += 0x7fffu + ((u >> 16) & 1u);
  return (unsigned short)(u >> 16);
}
__device__ __forceinline__ float bf2f(unsigned short s) {
  return __uint_as_float(((unsigned)s) << 16);
}
__device__ __forceinline__ float fast_tanh(float v) {
  float z = __expf(2.0f * v);
  return 1.0f - __fdividef(2.0f, z + 1.0f);
}

// ws layout (bytes)
#define WT_OFF   0         // 32768: bf16 Wsum^T [u][d]
#define BIAS_OFF 33280     // 512:   bias sum
#define MW_OFF   33792     // 8192:  per-chunk max
#define LW_OFF   41984     // 8192:  per-chunk expsum
#define EW_OFF   50176     // 524288: per-chunk e[64]
#define AW_OFF   574464    // 8192:  per-chunk alpha

// One-shot: Wt[u][d] = bf16(W1[d][u] + W2[d][u]); bias[u] = b1[u]+b2[u]
__global__ void prep_kernel(const float* __restrict__ W1w, const float* __restrict__ W1b,
                            const float* __restrict__ W2w, const float* __restrict__ W2b,
                            unsigned short* __restrict__ wt_g, float* __restrict__ bias_g)
{
  int i = blockIdx.x * 256 + threadIdx.x;   // 16384 = 128*128
  int u = i >> 7, d = i & 127;
  float s = W1w[(size_t)d * UU + u] + W2w[(size_t)d * UU + u];
  wt_g[(size_t)u * DD + d] = f2bf(s);
  if (i < UU) bias_g[i] = W1b[i] + W2b[i];
}

// K1: scores only. 64 rows/block; stage x->LDS (swizzled bf16), MFMA GEMM,
// tanh+V dot, chunk-local softmax stats. Writes {m, l, e[64]} per chunk.
__global__ __launch_bounds__(256, 4)
void scores_kernel(const float* __restrict__ x,
                   const unsigned short* __restrict__ wt_g,
                   const float* __restrict__ bias_g,
                   const float* __restrict__ Vw,
                   float* __restrict__ mw, float* __restrict__ lw,
                   float* __restrict__ e_ws)
{
  __shared__ __align__(16) unsigned short xs[ROWS * DD];  // 16 KB swizzled bf16
  __shared__ __align__(16) float spart[4][ROWS];          // per-wave score partials

  const int tid = threadIdx.x;
  const int blk = blockIdx.x;
  const int rowbase = blk * ROWS;
  const int w = tid >> 6, l = tid & 63, lx = l & 15, lq = l >> 4;

  // ---- stage x: issue HBM/L3 loads first ----
  float4 xr[8];
  #pragma unroll
  for (int it = 0; it < 4; ++it) {
    int F = tid + 256 * it;            // 1024 granules of 8 elems
    int row = F >> 4, g = F & 15;
    const float* src = x + (size_t)(rowbase + row) * DD + g * 8;
    xr[2 * it]     = *reinterpret_cast<const float4*>(src);
    xr[2 * it + 1] = *reinterpret_cast<const float4*>(src + 4);
  }

  // ---- B fragments + V/bias for this wave's 32 u-columns (L2-hit) ----
  short8 Bf[2][4];
  float vs[2], bs[2];
  #pragma unroll
  for (int nf = 0; nf < 2; ++nf) {
    const int u = 32 * w + 16 * nf + lx;
    vs[nf] = Vw[u];
    bs[nf] = bias_g[u];
    #pragma unroll
    for (int kf = 0; kf < 4; ++kf)
      Bf[nf][kf] = *reinterpret_cast<const short8*>(
          wt_g + (size_t)u * DD + 32 * kf + 8 * lq);
  }

  // ---- cvt + swizzled LDS write ----
  #pragma unroll
  for (int it = 0; it < 4; ++it) {
    int F = tid + 256 * it;
    int row = F >> 4, g = F & 15;
    float4 v0 = xr[2 * it], v1 = xr[2 * it + 1];
    short8 pk;
    pk[0] = (short)f2bf(v0.x); pk[1] = (short)f2bf(v0.y);
    pk[2] = (short)f2bf(v0.z); pk[3] = (short)f2bf(v0.w);
    pk[4] = (short)f2bf(v1.x); pk[5] = (short)f2bf(v1.y);
    pk[6] = (short)f2bf(v1.z); pk[7] = (short)f2bf(v1.w);
    *reinterpret_cast<short8*>(xs + row * DD + ((g ^ (row & 15)) << 3)) = pk;
  }
  __syncthreads();

  // ---- GEMM: 64 rows x wave's 32 u; A from LDS, B from regs ----
  f32x4 acc[4][2];
  #pragma unroll
  for (int mf = 0; mf < 4; ++mf) {
    acc[mf][0] = (f32x4){0.f, 0.f, 0.f, 0.f};
    acc[mf][1] = (f32x4){0.f, 0.f, 0.f, 0.f};
  }
  #pragma unroll
  for (int kf = 0; kf < 4; ++kf) {
    const int gs8 = ((4 * kf + lq) ^ lx) << 3;   // swizzle key: row&15 == lx
    #pragma unroll
    for (int mf = 0; mf < 4; ++mf) {
      short8 a = *reinterpret_cast<const short8*>(xs + (16 * mf + lx) * DD + gs8);
      acc[mf][0] = __builtin_amdgcn_mfma_f32_16x16x32_bf16(a, Bf[0][kf], acc[mf][0], 0, 0, 0);
      acc[mf][1] = __builtin_amdgcn_mfma_f32_16x16x32_bf16(a, Bf[1][kf], acc[mf][1], 0, 0, 0);
    }
  }

  // ---- per-wave score partials over this wave's u ----
  #pragma unroll
  for (int mf = 0; mf < 4; ++mf) {
    #pragma unroll
    for (int r = 0; r < 4; ++r) {
      float p = vs[0] * fast_tanh(acc[mf][0][r] + bs[0])
              + vs[1] * fast_tanh(acc[mf][1][r] + bs[1]);
      p += __shfl_xor(p, 1);
      p += __shfl_xor(p, 2);
      p += __shfl_xor(p, 4);
      p += __shfl_xor(p, 8);
      if (lx == 0) spart[w][16 * mf + 4 * lq + r] = p;   // C/D row = 4lq+r
    }
  }
  __syncthreads();

  // ---- chunk softmax stats: row = lane ----
  float sv = (spart[0][l] + spart[1][l]) + (spart[2][l] + spart[3][l]);
  float m = sv;
  #pragma unroll
  for (int off = 1; off < 64; off <<= 1) m = fmaxf(m, __shfl_xor(m, off));
  float e = __expf(sv - m);
  float lsum = e;
  #pragma unroll
  for (int off = 1; off < 64; off <<= 1) lsum += __shfl_xor(lsum, off);

  if (w == 0) e_ws[(size_t)blk * ROWS + l] = e;
  if (tid == 0) { mw[blk] = m; lw[blk] = lsum; }
}

// K2: per-batch global softmax combine -> alpha per chunk; zero d_out.
__global__ void alpha_kernel(const float* __restrict__ mw, const float* __restrict__ lw,
                             float* __restrict__ aw, float* __restrict__ out)
{
  const int b = blockIdx.x;       // 64
  const int t = threadIdx.x;      // 128
  if (t < 128) out[(size_t)b * DD + t] = 0.0f;

  if (t < 64) {                   // one wave does the 32-chunk combine
    float mi = (t < NCHUNK) ? mw[b * NCHUNK + t] : -3.0e38f;
    float li = (t < NCHUNK) ? lw[b * NCHUNK + t] : 0.0f;
    float M = mi;
    #pragma unroll
    for (int off = 1; off < 32; off <<= 1) M = fmaxf(M, __shfl_xor(M, off));
    float term = (t < NCHUNK) ? __expf(mi - M) * li : 0.0f;
    float L = term;
    #pragma unroll
    for (int off = 1; off < 32; off <<= 1) L += __shfl_xor(L, off);
    if (t < NCHUNK) aw[b * NCHUNK + t] = __fdividef(__expf(mi - M), L);
  }
}

// K3: context. Pure stream: w[row]=alpha*e[row]; ctx += w*x directly from
// global (no LDS staging, one barrier, 128 atomicAdds per block).
__global__ __launch_bounds__(256, 8)
void context_kernel(const float* __restrict__ x,
                    const float* __restrict__ e_ws, const float* __restrict__ aw,
                    float* __restrict__ out)
{
  __shared__ __align__(16) float pctx[4][DD];

  const int tid = threadIdx.x;
  const int blk = blockIdx.x;          // 2048
  const int rowbase = blk * ROWS;
  const int b = blk >> 5;              // batch
  const int c = blk & 31;              // chunk
  const int w = tid >> 6, l = tid & 63;
  const int gd = tid & 15;             // d-granule (8 floats)
  const int tg = tid >> 4;             // 16 groups of 4 rows

  const float alpha = aw[b * NCHUNK + c];

  float ca[8];
  #pragma unroll
  for (int e2 = 0; e2 < 8; ++e2) ca[e2] = 0.0f;
  #pragma unroll
  for (int k = 0; k < 4; ++k) {
    const int row = tg * 4 + k;
    const float wgt = alpha * e_ws[(size_t)blk * ROWS + row];
    const float* src = x + (size_t)(rowbase + row) * DD + gd * 8;
    const float4 v0 = *reinterpret_cast<const float4*>(src);
    const float4 v1 = *reinterpret_cast<const float4*>(src + 4);
    ca[0] = fmaf(wgt, v0.x, ca[0]); ca[1] = fmaf(wgt, v0.y, ca[1]);
    ca[2] = fmaf(wgt, v0.z, ca[2]); ca[3] = fmaf(wgt, v0.w, ca[3]);
    ca[4] = fmaf(wgt, v1.x, ca[4]); ca[5] = fmaf(wgt, v1.y, ca[5]);
    ca[6] = fmaf(wgt, v1.z, ca[6]); ca[7] = fmaf(wgt, v1.w, ca[7]);
  }
  #pragma unroll
  for (int e2 = 0; e2 < 8; ++e2) {
    ca[e2] += __shfl_xor(ca[e2], 16);
    ca[e2] += __shfl_xor(ca[e2], 32);
  }
  if (l < 16) {     // gd == l for these lanes
    #pragma unroll
    for (int e2 = 0; e2 < 8; ++e2) pctx[w][l * 8 + e2] = ca[e2];
  }
  __syncthreads();

  if (tid < 128) {
    float c0 = (pctx[0][tid] + pctx[1][tid]) + (pctx[2][tid] + pctx[3][tid]);
    atomicAdd(&out[(size_t)b * DD + tid], c0);
  }
}

extern "C" void kernel_launch(void* const* d_in, const int* in_sizes, int n_in,
                              void* d_out, int out_size, void* d_ws, size_t ws_size,
                              hipStream_t stream)
{
  const float* x   = (const float*)d_in[0];
  const float* W1w = (const float*)d_in[1];
  const float* W1b = (const float*)d_in[2];
  const float* W2w = (const float*)d_in[3];
  const float* W2b = (const float*)d_in[4];
  const float* Vw  = (const float*)d_in[5];
  // d_in[6] = V_b: constant on scores, cancels in softmax.

  const int bt = in_sizes[0] / DD;       // 131072
  const int nblk = bt / ROWS;            // 2048
  const int B = bt / SEQ_T;              // 64

  char* ws = (char*)d_ws;
  unsigned short* wt_g = (unsigned short*)(ws + WT_OFF);
  float* bias_g = (float*)(ws + BIAS_OFF);
  float* mw   = (float*)(ws + MW_OFF);
  float* lw   = (float*)(ws + LW_OFF);
  float* e_ws = (float*)(ws + EW_OFF);
  float* aw   = (float*)(ws + AW_OFF);
  float* out  = (float*)d_out;

  prep_kernel<<<64, 256, 0, stream>>>(W1w, W1b, W2w, W2b, wt_g, bias_g);
  scores_kernel<<<nblk, 256, 0, stream>>>(x, wt_g, bias_g, Vw, mw, lw, e_ws);
  alpha_kernel<<<B, 128, 0, stream>>>(mw, lw, aw, out);
  context_kernel<<<nblk, 256, 0, stream>>>(x, e_ws, aw, out);
}

// Round 11
// 39.247 us; speedup vs baseline: 1.5209x; 1.0382x over previous
//
#include <hip/hip_runtime.h>
#include <hip/hip_bf16.h>

// B=64, T=2048, D=U=128 (fixed shape)
#define DD 128
#define UU 128
#define SEQ_T 2048
#define ROWS 64           // rows per score-chunk
#define NCHUNK 32         // chunks per batch (SEQ_T/ROWS)

typedef __attribute__((ext_vector_type(8))) short short8;   // 8 bf16
typedef __attribute__((ext_vector_type(4))) float f32x4;    // MFMA C/D

__device__ __forceinline__ unsigned short f2bf(float f) {   // RNE fp32->bf16
  unsigned u = __float_as_uint(f);
  u += 0x7fffu + ((u >> 16) & 1u);
  return (unsigned short)(u >> 16);
}
__device__ __forceinline__ float bf2f(unsigned short s) {
  return __uint_as_float(((unsigned)s) << 16);
}
__device__ __forceinline__ float fast_tanh(float v) {
  float z = __expf(2.0f * v);
  return 1.0f - __fdividef(2.0f, z + 1.0f);
}

// ws layout (bytes)
#define WT_OFF   0         // 32768: bf16 Wsum^T [u][d]
#define BIAS_OFF 33280     // 512:   bias sum
#define MW_OFF   33792     // 8192:  per-chunk max
#define LW_OFF   41984     // 8192:  per-chunk expsum
#define EW_OFF   50176     // 524288: per-chunk e[64]

// One-shot: Wt[u][d] = bf16(W1[d][u] + W2[d][u]); bias[u] = b1[u]+b2[u];
// also zero d_out (context kernel accumulates with atomics every replay).
__global__ void prep_kernel(const float* __restrict__ W1w, const float* __restrict__ W1b,
                            const float* __restrict__ W2w, const float* __restrict__ W2b,
                            unsigned short* __restrict__ wt_g, float* __restrict__ bias_g,
                            float* __restrict__ out)
{
  int i = blockIdx.x * 256 + threadIdx.x;   // 16384 = 128*128
  int u = i >> 7, d = i & 127;
  float s = W1w[(size_t)d * UU + u] + W2w[(size_t)d * UU + u];
  wt_g[(size_t)u * DD + d] = f2bf(s);
  if (i < UU) bias_g[i] = W1b[i] + W2b[i];
  if (threadIdx.x < 128) out[(size_t)blockIdx.x * DD + threadIdx.x] = 0.0f;  // 64 blocks x 128
}

// K1: scores only. 64 rows/block; stage x->LDS (swizzled bf16), MFMA GEMM,
// tanh+V dot, chunk-local softmax stats. Writes {m, l, e[64]} per chunk.
__global__ __launch_bounds__(256, 4)
void scores_kernel(const float* __restrict__ x,
                   const unsigned short* __restrict__ wt_g,
                   const float* __restrict__ bias_g,
                   const float* __restrict__ Vw,
                   float* __restrict__ mw, float* __restrict__ lw,
                   float* __restrict__ e_ws)
{
  __shared__ __align__(16) unsigned short xs[ROWS * DD];  // 16 KB swizzled bf16
  __shared__ __align__(16) float spart[4][ROWS];          // per-wave score partials

  const int tid = threadIdx.x;
  const int blk = blockIdx.x;
  const int rowbase = blk * ROWS;
  const int w = tid >> 6, l = tid & 63, lx = l & 15, lq = l >> 4;

  // ---- stage x: issue HBM/L3 loads first ----
  float4 xr[8];
  #pragma unroll
  for (int it = 0; it < 4; ++it) {
    int F = tid + 256 * it;            // 1024 granules of 8 elems
    int row = F >> 4, g = F & 15;
    const float* src = x + (size_t)(rowbase + row) * DD + g * 8;
    xr[2 * it]     = *reinterpret_cast<const float4*>(src);
    xr[2 * it + 1] = *reinterpret_cast<const float4*>(src + 4);
  }

  // ---- B fragments + V/bias for this wave's 32 u-columns (L2-hit) ----
  short8 Bf[2][4];
  float vs[2], bs[2];
  #pragma unroll
  for (int nf = 0; nf < 2; ++nf) {
    const int u = 32 * w + 16 * nf + lx;
    vs[nf] = Vw[u];
    bs[nf] = bias_g[u];
    #pragma unroll
    for (int kf = 0; kf < 4; ++kf)
      Bf[nf][kf] = *reinterpret_cast<const short8*>(
          wt_g + (size_t)u * DD + 32 * kf + 8 * lq);
  }

  // ---- cvt + swizzled LDS write ----
  #pragma unroll
  for (int it = 0; it < 4; ++it) {
    int F = tid + 256 * it;
    int row = F >> 4, g = F & 15;
    float4 v0 = xr[2 * it], v1 = xr[2 * it + 1];
    short8 pk;
    pk[0] = (short)f2bf(v0.x); pk[1] = (short)f2bf(v0.y);
    pk[2] = (short)f2bf(v0.z); pk[3] = (short)f2bf(v0.w);
    pk[4] = (short)f2bf(v1.x); pk[5] = (short)f2bf(v1.y);
    pk[6] = (short)f2bf(v1.z); pk[7] = (short)f2bf(v1.w);
    *reinterpret_cast<short8*>(xs + row * DD + ((g ^ (row & 15)) << 3)) = pk;
  }
  __syncthreads();

  // ---- GEMM: 64 rows x wave's 32 u; A from LDS, B from regs ----
  f32x4 acc[4][2];
  #pragma unroll
  for (int mf = 0; mf < 4; ++mf) {
    acc[mf][0] = (f32x4){0.f, 0.f, 0.f, 0.f};
    acc[mf][1] = (f32x4){0.f, 0.f, 0.f, 0.f};
  }
  #pragma unroll
  for (int kf = 0; kf < 4; ++kf) {
    const int gs8 = ((4 * kf + lq) ^ lx) << 3;   // swizzle key: row&15 == lx
    #pragma unroll
    for (int mf = 0; mf < 4; ++mf) {
      short8 a = *reinterpret_cast<const short8*>(xs + (16 * mf + lx) * DD + gs8);
      acc[mf][0] = __builtin_amdgcn_mfma_f32_16x16x32_bf16(a, Bf[0][kf], acc[mf][0], 0, 0, 0);
      acc[mf][1] = __builtin_amdgcn_mfma_f32_16x16x32_bf16(a, Bf[1][kf], acc[mf][1], 0, 0, 0);
    }
  }

  // ---- per-wave score partials over this wave's u ----
  #pragma unroll
  for (int mf = 0; mf < 4; ++mf) {
    #pragma unroll
    for (int r = 0; r < 4; ++r) {
      float p = vs[0] * fast_tanh(acc[mf][0][r] + bs[0])
              + vs[1] * fast_tanh(acc[mf][1][r] + bs[1]);
      p += __shfl_xor(p, 1);
      p += __shfl_xor(p, 2);
      p += __shfl_xor(p, 4);
      p += __shfl_xor(p, 8);
      if (lx == 0) spart[w][16 * mf + 4 * lq + r] = p;   // C/D row = 4lq+r
    }
  }
  __syncthreads();

  // ---- chunk softmax stats: row = lane ----
  float sv = (spart[0][l] + spart[1][l]) + (spart[2][l] + spart[3][l]);
  float m = sv;
  #pragma unroll
  for (int off = 1; off < 64; off <<= 1) m = fmaxf(m, __shfl_xor(m, off));
  float e = __expf(sv - m);
  float lsum = e;
  #pragma unroll
  for (int off = 1; off < 64; off <<= 1) lsum += __shfl_xor(lsum, off);

  if (w == 0) e_ws[(size_t)blk * ROWS + l] = e;
  if (tid == 0) { mw[blk] = m; lw[blk] = lsum; }
}

// K3: context, with the per-batch softmax combine inlined (no alpha kernel).
// Each wave redundantly reduces the 32 (m,l) pairs of its batch (L2-hit),
// then streams x weighted by alpha*e; 128 atomicAdds per block.
__global__ __launch_bounds__(256, 8)
void context_kernel(const float* __restrict__ x,
                    const float* __restrict__ mw, const float* __restrict__ lw,
                    const float* __restrict__ e_ws,
                    float* __restrict__ out)
{
  __shared__ __align__(16) float pctx[4][DD];

  const int tid = threadIdx.x;
  const int blk = blockIdx.x;          // 2048
  const int rowbase = blk * ROWS;
  const int b = blk >> 5;              // batch
  const int c = blk & 31;              // chunk
  const int w = tid >> 6, l = tid & 63;
  const int gd = tid & 15;             // d-granule (8 floats)
  const int tg = tid >> 4;             // 16 groups of 4 rows

  // ---- inline alpha: global softmax combine over this batch's 32 chunks ----
  float mi = mw[b * NCHUNK + (l & 31)];
  float li = lw[b * NCHUNK + (l & 31)];
  float M = mi;
  #pragma unroll
  for (int off = 1; off < 32; off <<= 1) M = fmaxf(M, __shfl_xor(M, off));
  float term = __expf(mi - M) * li;
  float L = term;
  #pragma unroll
  for (int off = 1; off < 32; off <<= 1) L += __shfl_xor(L, off);
  const float mc = __shfl(mi, c & 31);            // this chunk's max
  const float alpha = __fdividef(__expf(mc - M), L);

  float ca[8];
  #pragma unroll
  for (int e2 = 0; e2 < 8; ++e2) ca[e2] = 0.0f;
  #pragma unroll
  for (int k = 0; k < 4; ++k) {
    const int row = tg * 4 + k;
    const float wgt = alpha * e_ws[(size_t)blk * ROWS + row];
    const float* src = x + (size_t)(rowbase + row) * DD + gd * 8;
    const float4 v0 = *reinterpret_cast<const float4*>(src);
    const float4 v1 = *reinterpret_cast<const float4*>(src + 4);
    ca[0] = fmaf(wgt, v0.x, ca[0]); ca[1] = fmaf(wgt, v0.y, ca[1]);
    ca[2] = fmaf(wgt, v0.z, ca[2]); ca[3] = fmaf(wgt, v0.w, ca[3]);
    ca[4] = fmaf(wgt, v1.x, ca[4]); ca[5] = fmaf(wgt, v1.y, ca[5]);
    ca[6] = fmaf(wgt, v1.z, ca[6]); ca[7] = fmaf(wgt, v1.w, ca[7]);
  }
  #pragma unroll
  for (int e2 = 0; e2 < 8; ++e2) {
    ca[e2] += __shfl_xor(ca[e2], 16);
    ca[e2] += __shfl_xor(ca[e2], 32);
  }
  if (l < 16) {     // gd == l for these lanes
    #pragma unroll
    for (int e2 = 0; e2 < 8; ++e2) pctx[w][l * 8 + e2] = ca[e2];
  }
  __syncthreads();

  if (tid < 128) {
    float c0 = (pctx[0][tid] + pctx[1][tid]) + (pctx[2][tid] + pctx[3][tid]);
    atomicAdd(&out[(size_t)b * DD + tid], c0);
  }
}

extern "C" void kernel_launch(void* const* d_in, const int* in_sizes, int n_in,
                              void* d_out, int out_size, void* d_ws, size_t ws_size,
                              hipStream_t stream)
{
  const float* x   = (const float*)d_in[0];
  const float* W1w = (const float*)d_in[1];
  const float* W1b = (const float*)d_in[2];
  const float* W2w = (const float*)d_in[3];
  const float* W2b = (const float*)d_in[4];
  const float* Vw  = (const float*)d_in[5];
  // d_in[6] = V_b: constant on scores, cancels in softmax.

  const int bt = in_sizes[0] / DD;       // 131072
  const int nblk = bt / ROWS;            // 2048

  char* ws = (char*)d_ws;
  unsigned short* wt_g = (unsigned short*)(ws + WT_OFF);
  float* bias_g = (float*)(ws + BIAS_OFF);
  float* mw   = (float*)(ws + MW_OFF);
  float* lw   = (float*)(ws + LW_OFF);
  float* e_ws = (float*)(ws + EW_OFF);
  float* out  = (float*)d_out;

  prep_kernel<<<64, 256, 0, stream>>>(W1w, W1b, W2w, W2b, wt_g, bias_g, out);
  scores_kernel<<<nblk, 256, 0, stream>>>(x, wt_g, bias_g, Vw, mw, lw, e_ws);
  context_kernel<<<nblk, 256, 0, stream>>>(x, mw, lw, e_ws, out);
}